// Round 14
// baseline (383.507 us; speedup 1.0000x reference)
//
#include <hip/hip_runtime.h>

typedef unsigned short u16;
typedef __attribute__((ext_vector_type(8))) short bf16x8;
typedef __attribute__((ext_vector_type(8))) unsigned short u16x8;
typedef __attribute__((ext_vector_type(4))) float f32x4;
typedef __attribute__((ext_vector_type(4))) unsigned int u32x4;

#define AS1 __attribute__((address_space(1)))
#define AS3 __attribute__((address_space(3)))

static __device__ __forceinline__ u16 f2bf(float f) {
  unsigned u = __float_as_uint(f);
  u += 0x7FFFu + ((u >> 16) & 1u);   // RNE
  return (u16)(u >> 16);
}

// ---------- weight fp32 -> bf16 + ksum zeroing (tiny, one launch) ----------
// blocks 0-1535: convert Wq/Wk/Wv ; blocks 1536-1543: zero ksum.
__global__ __launch_bounds__(256) void conv_w2(
    const float* __restrict__ wq, const float* __restrict__ wk,
    const float* __restrict__ wv,
    u16* __restrict__ oq, u16* __restrict__ ok, u16* __restrict__ ov,
    float* __restrict__ ksum) {
  const int bx = blockIdx.x;
  if (bx < 1536) {
    const int sel = bx >> 9;           // 0..2
    const int i = (bx & 511) * 256 + threadIdx.x;
    const float* in = sel == 0 ? wq : (sel == 1 ? wk : wv);
    u16* out = sel == 0 ? oq : (sel == 1 ? ok : ov);
    const float4* p = (const float4*)in + (size_t)i * 2;
    float4 a = p[0], b = p[1];
    u16x8 r;
    r[0] = f2bf(a.x); r[1] = f2bf(a.y); r[2] = f2bf(a.z); r[3] = f2bf(a.w);
    r[4] = f2bf(b.x); r[5] = f2bf(b.y); r[6] = f2bf(b.z); r[7] = f2bf(b.w);
    ((u16x8*)out)[i] = r;
  } else {
    const int i = (bx - 1536) * 256 + threadIdx.x;  // 0..2047
#pragma unroll
    for (int j = 0; j < 8; ++j) ksum[i * 8 + j] = 0.f;
  }
}

enum { M_BIASN = 0, M_BIASM = 1, M_SCORES = 2, M_OUT = 3 };

// =============== 128x128 bf16 GEMM core (m97 + T2 swizzle) ===============
// C = A(MxK) * B(NxK)^T. 256 thr / 4 waves, single 32KB LDS, BK=64.
// F32A/F32B: that operand is read from fp32 global and reg-staged
// (global_load_dwordx4 -> v_cvt_pk_bf16_f32 -> swizzled ds_write_b128) into
// the SAME bf16 LDS layout; the other operand keeps global_load_lds w16 with
// inverse-swizzled source. Fuses the fp32->bf16 conversion into the GEMM.
template <int MODE, int F32A, int F32B>
static __device__ __forceinline__ void core128(
    const u16* __restrict__ Ab, const float* __restrict__ Af, int lda,
    const u16* __restrict__ Bb, const float* __restrict__ Bf, int ldb,
    char* smem, int m0, int n0, int nk, void* __restrict__ Cbase, int ldc,
    const float* __restrict__ bias, const float* __restrict__ ksb,
    const float* __restrict__ vtab, float* __restrict__ ksum_acc) {
  const int tid = threadIdx.x;
  const int lane = tid & 63;
  const int wid = tid >> 6;
  const int wm = wid >> 1, wn = wid & 1;

  char* As = smem;           // 128 rows x 128B = 16KB
  char* Bs = smem + 16384;   // 16KB

  const int rbase_st = tid >> 3;                 // 0..31 (global_load_lds path)
  const int gcol = ((tid & 7) << 4) ^ ((rbase_st & 7) << 4);

  // reg-staging geometry: thread t owns row t>>1, 32-float half (t&1)
  const int srow = tid >> 1;
  const int shalf = (tid & 1) * 32;              // float col base
  char* sdstA = As + srow * 128;
  char* sdstB = Bs + srow * 128;

  const int aoff = (wm * 64 + (lane & 15)) * 128;
  const int boff = (wn * 64 + (lane & 15)) * 128;
  const int c0 = ((0 * 4 + (lane >> 4)) ^ (lane & 7)) << 4;
  const int c1 = ((1 * 4 + (lane >> 4)) ^ (lane & 7)) << 4;

  f32x4 acc[4][4];
#pragma unroll
  for (int m = 0; m < 4; ++m)
#pragma unroll
    for (int n = 0; n < 4; ++n) acc[m][n] = (f32x4){0.f, 0.f, 0.f, 0.f};

  for (int kt = 0; kt < nk; ++kt) {
    const int k0 = kt * 64;
    float4 va[8], vb[8];
    // issue fp32 reg-stage loads first (deepest latency), then LDS-direct
    if (F32A) {
      const float4* ga = (const float4*)(Af + (size_t)(m0 + srow) * lda + k0 + shalf);
#pragma unroll
      for (int i = 0; i < 8; ++i) va[i] = ga[i];
    }
    if (F32B) {
      const float4* gb = (const float4*)(Bf + (size_t)(n0 + srow) * ldb + k0 + shalf);
#pragma unroll
      for (int i = 0; i < 8; ++i) vb[i] = gb[i];
    }
    if (!F32A) {
#pragma unroll
      for (int i = 0; i < 4; ++i) {
        const char* ga = (const char*)(Ab + (size_t)(m0 + i * 32 + rbase_st) * lda + k0) + gcol;
        __builtin_amdgcn_global_load_lds(
            (const AS1 void*)ga, (AS3 void*)(As + i * 4096 + wid * 1024), 16, 0, 0);
      }
    }
    if (!F32B) {
#pragma unroll
      for (int i = 0; i < 4; ++i) {
        const char* gb = (const char*)(Bb + (size_t)(n0 + i * 32 + rbase_st) * ldb + k0) + gcol;
        __builtin_amdgcn_global_load_lds(
            (const AS1 void*)gb, (AS3 void*)(Bs + i * 4096 + wid * 1024), 16, 0, 0);
      }
    }
    if (F32A) {
      unsigned w[16];
#pragma unroll
      for (int i = 0; i < 8; ++i) {
        asm("v_cvt_pk_bf16_f32 %0, %1, %2" : "=v"(w[2 * i]) : "v"(va[i].x), "v"(va[i].y));
        asm("v_cvt_pk_bf16_f32 %0, %1, %2" : "=v"(w[2 * i + 1]) : "v"(va[i].z), "v"(va[i].w));
      }
#pragma unroll
      for (int u = 0; u < 4; ++u) {
        const int c = shalf * 2 + u * 16;  // byte col
        *(u32x4*)(sdstA + (c ^ ((srow & 7) << 4))) =
            (u32x4){w[4 * u], w[4 * u + 1], w[4 * u + 2], w[4 * u + 3]};
      }
    }
    if (F32B) {
      unsigned w[16];
#pragma unroll
      for (int i = 0; i < 8; ++i) {
        asm("v_cvt_pk_bf16_f32 %0, %1, %2" : "=v"(w[2 * i]) : "v"(vb[i].x), "v"(vb[i].y));
        asm("v_cvt_pk_bf16_f32 %0, %1, %2" : "=v"(w[2 * i + 1]) : "v"(vb[i].z), "v"(vb[i].w));
      }
#pragma unroll
      for (int u = 0; u < 4; ++u) {
        const int c = shalf * 2 + u * 16;
        *(u32x4*)(sdstB + (c ^ ((srow & 7) << 4))) =
            (u32x4){w[4 * u], w[4 * u + 1], w[4 * u + 2], w[4 * u + 3]};
      }
    }
    __syncthreads();   // drains global_load_lds (vmcnt) + ds_write (lgkm)
#pragma unroll
    for (int ks = 0; ks < 2; ++ks) {
      const int cks = ks ? c1 : c0;
      bf16x8 af[4], bfv[4];
#pragma unroll
      for (int m = 0; m < 4; ++m) af[m] = *(const bf16x8*)(As + aoff + m * 2048 + cks);
#pragma unroll
      for (int n = 0; n < 4; ++n) bfv[n] = *(const bf16x8*)(Bs + boff + n * 2048 + cks);
#pragma unroll
      for (int m = 0; m < 4; ++m)
#pragma unroll
        for (int n = 0; n < 4; ++n)
          acc[m][n] = __builtin_amdgcn_mfma_f32_16x16x32_bf16(af[m], bfv[n], acc[m][n], 0, 0, 0);
    }
    __syncthreads();
  }

  // epilogue — C/D layout: col = lane&15, row = (lane>>4)*4 + reg  [m89]
  u16* C16 = (u16*)Cbase;
  float* Cf = (float*)Cbase;
  float rs[4][4];
  if (MODE == M_BIASN && ksum_acc) {
#pragma unroll
    for (int m = 0; m < 4; ++m)
#pragma unroll
      for (int j = 0; j < 4; ++j) rs[m][j] = 0.f;
  }
#pragma unroll
  for (int m = 0; m < 4; ++m) {
#pragma unroll
    for (int n = 0; n < 4; ++n) {
      const int rb = m0 + wm * 64 + m * 16 + ((lane >> 4) << 2);
      const int c = n0 + wn * 64 + n * 16 + (lane & 15);
#pragma unroll
      for (int j = 0; j < 4; ++j) {
        const int r = rb + j;
        float v = acc[m][n][j];
        if (MODE == M_BIASN) {
          v += bias[c];
          if (ksum_acc) rs[m][j] += v;
          C16[(size_t)r * ldc + c] = f2bf(v);
        } else if (MODE == M_BIASM) {
          v += bias[r];
          C16[(size_t)r * ldc + c] = f2bf(v);
        } else if (MODE == M_SCORES) {
          if (c <= r) v += ksb[r] * vtab[r - c];  // rel = t-s >= 0
          else v = 0.f;                           // causal mask
          C16[(size_t)r * ldc + c] = f2bf(v);
        } else {  // M_OUT
          Cf[(size_t)r * ldc + c] = v;
        }
      }
    }
  }
  if (MODE == M_BIASN && ksum_acc) {
#pragma unroll
    for (int m = 0; m < 4; ++m) {
      const int rb = m0 + wm * 64 + m * 16 + ((lane >> 4) << 2);
#pragma unroll
      for (int j = 0; j < 4; ++j) {
        float s = rs[m][j];
        s += __shfl_xor(s, 1);
        s += __shfl_xor(s, 2);
        s += __shfl_xor(s, 4);
        s += __shfl_xor(s, 8);
        if ((lane & 15) == 0) atomicAdd(&ksum_acc[rb + j], s);
      }
    }
  }
}

// ---- Q+K+V projections, conversion fused: flat 3072 blocks, per-XCD strips.
// Q (idx 0-127): A = e fp32 reg-staged; K (128-255): A = res fp32 (+ksum fold);
// V (256-383): A = Wv bf16, B = e fp32 reg-staged.
__global__ __launch_bounds__(256, 4) void k_qkv_proj(
    const float* e, const float* res, const u16* Wq, const u16* Wk, const u16* Wv,
    const float* bq, const float* bk, const float* bv,
    u16* Q, u16* K, u16* VT, float* ksum) {
  const int l = blockIdx.x;
  const int xcd = l & 7;
  const int idx = l >> 3;            // 0..383
  const int j = idx & 127;
  __shared__ char smem[32768];
  if (idx < 256) {
    const bool isK = idx >= 128;
    const int gy = xcd * 16 + (j >> 3);  // m-tile in [0,128)
    const int gx = j & 7;                // n-tile in [0,8)
    core128<M_BIASN, 1, 0>(nullptr, isK ? res : e, 1024,
                           isK ? Wk : Wq, nullptr, 1024, smem,
                           gy * 128, gx * 128, 16, isK ? K : Q, 1024,
                           isK ? bk : bq, nullptr, nullptr, isK ? ksum : nullptr);
  } else {
    const int gxt = xcd * 16 + (j >> 3);  // t-tile in [0,128)
    const int gyd = j & 7;                // d-tile in [0,8)
    core128<M_BIASM, 0, 1>(Wv, nullptr, 1024, nullptr, e, 1024, smem,
                           gyd * 128, gxt * 128, 16,
                           VT, 16384, bv, nullptr, nullptr, nullptr);
  }
}
// ---- scores: flat 1088 blocks. xcd = l&7 = z (batch pinned to XCD).
__global__ __launch_bounds__(256, 4) void k_scores(
    const u16* Q, const u16* K, u16* S, const float* ksum, const float* vtab) {
  const int l = blockIdx.x;
  const int z = l & 7;
  const int h = l >> 3;
  int gy = 0;
#pragma unroll
  for (int q = 1; q < 16; ++q) if (q * (q + 1) / 2 <= h) gy = q;
  const int gx = h - gy * (gy + 1) / 2;  // gx <= gy
  __shared__ char smem[32768];
  core128<M_SCORES, 0, 0>(Q + (size_t)z * 2048 * 1024, nullptr, 1024,
                          K + (size_t)z * 2048 * 1024, nullptr, 1024, smem,
                          gy * 128, gx * 128, 16,
                          S + (size_t)z * 2048 * 2048, 2048,
                          nullptr, ksum + (size_t)z * 2048, vtab, nullptr);
}
// ---- out: flat 1024 blocks. xcd = z. Snake-balanced K-extents.
__global__ __launch_bounds__(256, 4) void k_out(
    const u16* S, const u16* VT, float* O) {
  const int l = blockIdx.x;
  const int z = l & 7;
  const int idx = l >> 3;              // 0..127
  const int r = idx >> 5;              // CU round 0..3
  const int p = idx & 31;
  const int rank = (r << 5) | ((r & 1) ? (31 - p) : p);  // snake over desc list
  const int gy = 15 - (rank >> 3);     // q-tile
  const int gx = rank & 7;             // d-tile
  const int nk = (gy + 1) * 2;         // causal extent (gy+1)*128 score-cols
  __shared__ char smem[32768];
  core128<M_OUT, 0, 0>(S + (size_t)z * 2048 * 2048, nullptr, 2048,
                       VT + (size_t)z * 2048, nullptr, 16384, smem,
                       gy * 128, gx * 128, nk,
                       O + (size_t)z * 2048 * 1024, 1024,
                       nullptr, nullptr, nullptr, nullptr);
}

extern "C" void kernel_launch(void* const* d_in, const int* in_sizes, int n_in,
                              void* d_out, int out_size, void* d_ws, size_t ws_size,
                              hipStream_t stream) {
  (void)in_sizes; (void)n_in; (void)out_size; (void)ws_size;
  const float* e    = (const float*)d_in[0];
  const float* res  = (const float*)d_in[1];
  const float* Wq_w = (const float*)d_in[2];
  const float* Wq_b = (const float*)d_in[3];
  const float* Wk_w = (const float*)d_in[4];
  const float* Wk_b = (const float*)d_in[5];
  const float* Wv_w = (const float*)d_in[6];
  const float* Wv_b = (const float*)d_in[7];
  const float* vtab = (const float*)d_in[8];

  char* ws = (char*)d_ws;
  const size_t SZ = 33554432;  // 32 MiB
  u16* scores = (u16*)(ws);            // 64 MiB (slots 0-1)
  u16* Qb  = (u16*)(ws + 2 * SZ);
  u16* Kb  = (u16*)(ws + 3 * SZ);
  u16* VT  = (u16*)(ws + 4 * SZ);
  u16* Wqb = (u16*)(ws + 5 * SZ);
  u16* Wkb = (u16*)(ws + 5 * SZ + 2097152);
  u16* Wvb = (u16*)(ws + 5 * SZ + 2 * 2097152);
  float* ksum = (float*)(ws + 5 * SZ + 3 * 2097152);

  // weight conversion + ksum zeroing (tiny)
  conv_w2<<<dim3(1544, 1, 1), 256, 0, stream>>>(Wq_w, Wk_w, Wv_w, Wqb, Wkb, Wvb, ksum);

  // Q/K/V projections with fused fp32->bf16 (K-phase folds ksum)
  k_qkv_proj<<<dim3(3072, 1, 1), 256, 0, stream>>>(e, res, Wqb, Wkb, Wvb,
                                                   Wq_b, Wk_b, Wv_b, Qb, Kb, VT, ksum);

  // scores: 1088 flat blocks, batch z pinned to XCD z
  k_scores<<<dim3(1088, 1, 1), 256, 0, stream>>>(Qb, Kb, scores, ksum, vtab);

  // out: 1024 flat blocks, batch z pinned to XCD z, snake-balanced K-extents
  k_out<<<dim3(1024, 1, 1), 256, 0, stream>>>(scores, VT, (float*)d_out);
}

// Round 15
// 248.423 us; speedup vs baseline: 1.5438x; 1.5438x over previous
//
#include <hip/hip_runtime.h>

typedef unsigned short u16;
typedef __attribute__((ext_vector_type(8))) short bf16x8;
typedef __attribute__((ext_vector_type(8))) unsigned short u16x8;
typedef __attribute__((ext_vector_type(4))) float f32x4;

#define AS1 __attribute__((address_space(1)))
#define AS3 __attribute__((address_space(3)))

static __device__ __forceinline__ u16 f2bf(float f) {
  unsigned u = __float_as_uint(f);
  u += 0x7FFFu + ((u >> 16) & 1u);   // RNE
  return (u16)(u >> 16);
}

// ---------- fused fp32 -> bf16 conversion (one launch) ----------
// z=0: e -> ebf ; z=1: res -> rbf ; z=2: blocks 0-1535 convert Wq/Wk/Wv,
// blocks 1536-1543 zero ksum (graph-replay determinism), rest exit.
__global__ __launch_bounds__(256) void conv_all(
    const float* __restrict__ e, const float* __restrict__ res,
    const float* __restrict__ wq, const float* __restrict__ wk,
    const float* __restrict__ wv,
    u16* __restrict__ eb, u16* __restrict__ rb,
    u16* __restrict__ oq, u16* __restrict__ ok, u16* __restrict__ ov,
    float* __restrict__ ksum) {
  const int z = blockIdx.z;
  if (z < 2) {
    int i = blockIdx.x * 256 + threadIdx.x;
    const float* in = z ? res : e;
    u16* out = z ? rb : eb;
    const float4* p = (const float4*)in + (size_t)i * 2;
    float4 a = p[0], b = p[1];
    u16x8 r;
    r[0] = f2bf(a.x); r[1] = f2bf(a.y); r[2] = f2bf(a.z); r[3] = f2bf(a.w);
    r[4] = f2bf(b.x); r[5] = f2bf(b.y); r[6] = f2bf(b.z); r[7] = f2bf(b.w);
    ((u16x8*)out)[i] = r;
    return;
  }
  const int bx = blockIdx.x;
  if (bx < 1536) {
    const int sel = bx >> 9;           // 0..2
    const int i = (bx & 511) * 256 + threadIdx.x;
    const float* in = sel == 0 ? wq : (sel == 1 ? wk : wv);
    u16* out = sel == 0 ? oq : (sel == 1 ? ok : ov);
    const float4* p = (const float4*)in + (size_t)i * 2;
    float4 a = p[0], b = p[1];
    u16x8 r;
    r[0] = f2bf(a.x); r[1] = f2bf(a.y); r[2] = f2bf(a.z); r[3] = f2bf(a.w);
    r[4] = f2bf(b.x); r[5] = f2bf(b.y); r[6] = f2bf(b.z); r[7] = f2bf(b.w);
    ((u16x8*)out)[i] = r;
  } else if (bx < 1544) {
    const int i = (bx - 1536) * 256 + threadIdx.x;  // 0..2047
#pragma unroll
    for (int j = 0; j < 8; ++j) ksum[i * 8 + j] = 0.f;
  }
}

enum { M_BIASN = 0, M_BIASM = 1, M_SCORES = 2, M_OUT = 3 };

// =============== 128x128 bf16 GEMM core (m97 + T2 swizzle) ===============
// C = A(MxK) * B(NxK)^T. 256 thr / 4 waves (2x2, wave tile 64x64, acc 4x4),
// single 32KB LDS, BK=64, global_load_lds w16 with inverse-swizzled source.
template <int MODE>
static __device__ __forceinline__ void core128(
    const u16* __restrict__ Ab, int lda, const u16* __restrict__ Bb, int ldb,
    char* smem, int m0, int n0, int nk, void* __restrict__ Cbase, int ldc,
    const float* __restrict__ bias, const float* __restrict__ ksb,
    const float* __restrict__ vtab, float* __restrict__ ksum_acc) {
  const int tid = threadIdx.x;
  const int lane = tid & 63;
  const int wid = tid >> 6;
  const int wm = wid >> 1, wn = wid & 1;

  char* As = smem;           // 128 rows x 128B = 16KB
  char* Bs = smem + 16384;   // 16KB

  const int rbase_st = tid >> 3;                 // 0..31
  const int gcol = ((tid & 7) << 4) ^ ((rbase_st & 7) << 4);

  const int aoff = (wm * 64 + (lane & 15)) * 128;
  const int boff = (wn * 64 + (lane & 15)) * 128;
  const int c0 = ((0 * 4 + (lane >> 4)) ^ (lane & 7)) << 4;
  const int c1 = ((1 * 4 + (lane >> 4)) ^ (lane & 7)) << 4;

  f32x4 acc[4][4];
#pragma unroll
  for (int m = 0; m < 4; ++m)
#pragma unroll
    for (int n = 0; n < 4; ++n) acc[m][n] = (f32x4){0.f, 0.f, 0.f, 0.f};

  for (int kt = 0; kt < nk; ++kt) {
    const int k0 = kt * 64;
#pragma unroll
    for (int i = 0; i < 4; ++i) {
      const char* ga = (const char*)(Ab + (size_t)(m0 + i * 32 + rbase_st) * lda + k0) + gcol;
      __builtin_amdgcn_global_load_lds(
          (const AS1 void*)ga, (AS3 void*)(As + i * 4096 + wid * 1024), 16, 0, 0);
    }
#pragma unroll
    for (int i = 0; i < 4; ++i) {
      const char* gb = (const char*)(Bb + (size_t)(n0 + i * 32 + rbase_st) * ldb + k0) + gcol;
      __builtin_amdgcn_global_load_lds(
          (const AS1 void*)gb, (AS3 void*)(Bs + i * 4096 + wid * 1024), 16, 0, 0);
    }
    __syncthreads();
#pragma unroll
    for (int ks = 0; ks < 2; ++ks) {
      const int cks = ks ? c1 : c0;
      bf16x8 af[4], bfv[4];
#pragma unroll
      for (int m = 0; m < 4; ++m) af[m] = *(const bf16x8*)(As + aoff + m * 2048 + cks);
#pragma unroll
      for (int n = 0; n < 4; ++n) bfv[n] = *(const bf16x8*)(Bs + boff + n * 2048 + cks);
#pragma unroll
      for (int m = 0; m < 4; ++m)
#pragma unroll
        for (int n = 0; n < 4; ++n)
          acc[m][n] = __builtin_amdgcn_mfma_f32_16x16x32_bf16(af[m], bfv[n], acc[m][n], 0, 0, 0);
    }
    __syncthreads();
  }

  // epilogue — C/D layout: col = lane&15, row = (lane>>4)*4 + reg  [m89]
  u16* C16 = (u16*)Cbase;
  float* Cf = (float*)Cbase;
  float rs[4][4];
  if (MODE == M_BIASN && ksum_acc) {
#pragma unroll
    for (int m = 0; m < 4; ++m)
#pragma unroll
      for (int j = 0; j < 4; ++j) rs[m][j] = 0.f;
  }
#pragma unroll
  for (int m = 0; m < 4; ++m) {
#pragma unroll
    for (int n = 0; n < 4; ++n) {
      const int rb = m0 + wm * 64 + m * 16 + ((lane >> 4) << 2);
      const int c = n0 + wn * 64 + n * 16 + (lane & 15);
#pragma unroll
      for (int j = 0; j < 4; ++j) {
        const int r = rb + j;
        float v = acc[m][n][j];
        if (MODE == M_BIASN) {
          v += bias[c];
          if (ksum_acc) rs[m][j] += v;
          C16[(size_t)r * ldc + c] = f2bf(v);
        } else if (MODE == M_BIASM) {
          v += bias[r];
          C16[(size_t)r * ldc + c] = f2bf(v);
        } else if (MODE == M_SCORES) {
          if (c <= r) v += ksb[r] * vtab[r - c];  // rel = t-s >= 0
          else v = 0.f;                           // causal mask
          C16[(size_t)r * ldc + c] = f2bf(v);
        } else {  // M_OUT
          Cf[(size_t)r * ldc + c] = v;
        }
      }
    }
  }
  if (MODE == M_BIASN && ksum_acc) {
#pragma unroll
    for (int m = 0; m < 4; ++m) {
      const int rb = m0 + wm * 64 + m * 16 + ((lane >> 4) << 2);
#pragma unroll
      for (int j = 0; j < 4; ++j) {
        float s = rs[m][j];
        s += __shfl_xor(s, 1);
        s += __shfl_xor(s, 2);
        s += __shfl_xor(s, 4);
        s += __shfl_xor(s, 8);
        if ((lane & 15) == 0) atomicAdd(&ksum_acc[rb + j], s);
      }
    }
  }
}

// ---- Q+K+V projections in ONE launch: flat 3072 blocks. xcd = l&7 owns
// token-rows [xcd*2048, +2048); idx selects phase: Q (0-127), K (128-255,
// folds ksum), V^T (256-383).
__global__ __launch_bounds__(256, 4) void k_qkv_proj(
    const u16* eb, const u16* rb, const u16* Wq, const u16* Wk, const u16* Wv,
    const float* bq, const float* bk, const float* bv,
    u16* Q, u16* K, u16* VT, float* ksum) {
  const int l = blockIdx.x;
  const int xcd = l & 7;
  const int idx = l >> 3;            // 0..383
  const int j = idx & 127;
  __shared__ char smem[32768];
  if (idx < 256) {
    const bool isK = idx >= 128;
    const int gy = xcd * 16 + (j >> 3);  // m-tile in [0,128)
    const int gx = j & 7;                // n-tile in [0,8)
    core128<M_BIASN>(isK ? rb : eb, 1024, isK ? Wk : Wq, 1024, smem,
                     gy * 128, gx * 128, 16, isK ? K : Q, 1024,
                     isK ? bk : bq, nullptr, nullptr, isK ? ksum : nullptr);
  } else {
    const int gxt = xcd * 16 + (j >> 3);  // t-tile in [0,128)
    const int gyd = j & 7;                // d-tile in [0,8)
    core128<M_BIASM>(Wv, 1024, eb, 1024, smem, gyd * 128, gxt * 128, 16,
                     VT, 16384, bv, nullptr, nullptr, nullptr);
  }
}
// ---- scores: flat 1088 blocks. xcd = l&7 = z (batch pinned to XCD).
__global__ __launch_bounds__(256, 4) void k_scores(
    const u16* Q, const u16* K, u16* S, const float* ksum, const float* vtab) {
  const int l = blockIdx.x;
  const int z = l & 7;
  const int h = l >> 3;
  int gy = 0;
#pragma unroll
  for (int q = 1; q < 16; ++q) if (q * (q + 1) / 2 <= h) gy = q;
  const int gx = h - gy * (gy + 1) / 2;  // gx <= gy
  __shared__ char smem[32768];
  core128<M_SCORES>(Q + (size_t)z * 2048 * 1024, 1024,
                    K + (size_t)z * 2048 * 1024, 1024, smem,
                    gy * 128, gx * 128, 16,
                    S + (size_t)z * 2048 * 2048, 2048,
                    nullptr, ksum + (size_t)z * 2048, vtab, nullptr);
}
// ---- out: flat 1024 blocks. xcd = z. Snake (boustrophedon) tile order over
// the desc-sorted tile list: every CU's four blocks sum to 68 K-steps.
__global__ __launch_bounds__(256, 4) void k_out(
    const u16* S, const u16* VT, float* O) {
  const int l = blockIdx.x;
  const int z = l & 7;
  const int idx = l >> 3;              // 0..127
  const int r = idx >> 5;              // CU round 0..3
  const int p = idx & 31;
  const int rank = (r << 5) | ((r & 1) ? (31 - p) : p);  // snake over desc list
  const int gy = 15 - (rank >> 3);     // q-tile
  const int gx = rank & 7;             // d-tile
  const int nk = (gy + 1) * 2;         // causal extent (gy+1)*128 score-cols
  __shared__ char smem[32768];
  core128<M_OUT>(S + (size_t)z * 2048 * 2048, 2048,
                 VT + (size_t)z * 2048, 16384, smem,
                 gy * 128, gx * 128, nk,
                 O + (size_t)z * 2048 * 1024, 1024,
                 nullptr, nullptr, nullptr, nullptr);
}

extern "C" void kernel_launch(void* const* d_in, const int* in_sizes, int n_in,
                              void* d_out, int out_size, void* d_ws, size_t ws_size,
                              hipStream_t stream) {
  (void)in_sizes; (void)n_in; (void)out_size; (void)ws_size;
  const float* e    = (const float*)d_in[0];
  const float* res  = (const float*)d_in[1];
  const float* Wq_w = (const float*)d_in[2];
  const float* Wq_b = (const float*)d_in[3];
  const float* Wk_w = (const float*)d_in[4];
  const float* Wk_b = (const float*)d_in[5];
  const float* Wv_w = (const float*)d_in[6];
  const float* Wv_b = (const float*)d_in[7];
  const float* vtab = (const float*)d_in[8];

  char* ws = (char*)d_ws;
  const size_t SZ = 33554432;  // 32 MiB = one bf16 (16384x1024) buffer
  u16* ebf = (u16*)(ws);
  u16* rbf = (u16*)(ws + SZ);
  u16* Qb  = (u16*)(ws + 2 * SZ);
  u16* Kb  = (u16*)(ws + 3 * SZ);
  u16* VT  = (u16*)(ws + 4 * SZ);
  u16* Wqb = (u16*)(ws + 5 * SZ);
  u16* Wkb = (u16*)(ws + 5 * SZ + 2097152);
  u16* Wvb = (u16*)(ws + 5 * SZ + 2 * 2097152);
  float* ksum = (float*)(ws + 5 * SZ + 3 * 2097152);
  u16* scores = (u16*)(ws);  // reuse ebf+rbf (64 MB); written after last read of ebf

  // all fp32->bf16 conversion + ksum zeroing in one launch
  conv_all<<<dim3(8192, 1, 3), 256, 0, stream>>>(e, res, Wq_w, Wk_w, Wv_w,
                                                 ebf, rbf, Wqb, Wkb, Wvb, ksum);

  // Q/K/V projections (K-phase folds ksum): 3072 flat blocks, per-XCD strips
  k_qkv_proj<<<dim3(3072, 1, 1), 256, 0, stream>>>(ebf, rbf, Wqb, Wkb, Wvb,
                                                   Wq_b, Wk_b, Wv_b, Qb, Kb, VT, ksum);

  // scores: 1088 flat blocks, batch z pinned to XCD z
  k_scores<<<dim3(1088, 1, 1), 256, 0, stream>>>(Qb, Kb, scores, ksum, vtab);

  // out: 1024 flat blocks, batch z pinned to XCD z, snake-balanced K-extents
  k_out<<<dim3(1024, 1, 1), 256, 0, stream>>>(scores, VT, (float*)d_out);
}